// Round 12
// baseline (298.901 us; speedup 1.0000x reference)
//
#include <hip/hip_runtime.h>
#include <hip/hip_fp16.h>
#include <math.h>

#define HW 512
#define MASK 511
#define IMG (512*512)
#define NSTEP 16
#define NSLICE 17

#define TR 84             // tile rows: [Y0-10, Y0+74)
#define TSTR 104          // ushort stride/row: 208 B = 13 granules (odd -> ~2-way, free)
#define WSB_OFF 32        // ushort offset of B-frag table in ws

typedef _Float16 half_t;
typedef __attribute__((ext_vector_type(8))) _Float16 f16x8;
typedef __attribute__((ext_vector_type(4))) float f32x4;

#define SBAR() __builtin_amdgcn_sched_barrier(0)

// B-frags (Toeplitz): frag f2 = dy*4 + v*2 + s  (v: dx-window, s: hi/lo split).
// lane l, elem j -> k = 8*(l>>4)+j, n = l&15, d = k-n.
// v=0: B[k][n] = W[dy][d-6]  for d in [6,15]  (dx 0..9,  A-window 16j)
// v=1: B[k][n] = W[dy][d+10] for d in [0,10]  (dx 10..20, A-window 16j+16)
// Same (lane,elem)->k map used for A => any fixed hardware k-permutation cancels.
__global__ void prep_kernel(const float* __restrict__ w1,
                            const float* __restrict__ w2,
                            const float* __restrict__ w3,
                            float* __restrict__ ws) {
    int tid = threadIdx.x;
    if (tid == 0) {
        // 1->10->1 MLP on nonneg scalar collapses: C = sum_o w3[o]*max(w2[o],0)
        float c = 0.f;
        for (int o = 0; o < 10; ++o) c += w3[o] * fmaxf(w2[o], 0.f);
        ws[0] = c;
    }
    half_t* wsb = (half_t*)((unsigned short*)ws + WSB_OFF);
    for (int u = tid; u < 84 * 512; u += blockDim.x) {
        int f2 = u >> 9, rem = u & 511, l = rem >> 3, j = rem & 7;
        int dy = f2 >> 2, v = (f2 >> 1) & 1, s = f2 & 1;
        int k = ((l >> 4) << 3) + j, n = l & 15, d = k - n;
        float wf = 0.f;
        if (v == 0) { if (d >= 6 && d <= 15) wf = w1[dy * 21 + d - 6]; }
        else        { if (d >= 0 && d <= 10) wf = w1[dy * 21 + d + 10]; }
        half_t h = (half_t)wf;
        wsb[u] = (s == 0) ? h : (half_t)(wf - (float)h);   // W = W_h + W_l
    }
}

__global__ void copy_kernel(const float* __restrict__ x, float* __restrict__ out) {
    int i = blockIdx.x * blockDim.x + threadIdx.x;   // float4 index
    if (i < 8 * 65536) {
        const float4* in4 = (const float4*)x;
        float4* out4 = (float4*)out;
        int b = i >> 16;
        int off = i & 65535;
        out4[(size_t)b * (NSLICE * 65536) + off] = in4[i];
    }
}

__global__ __launch_bounds__(256, 2)
void step_kernel(const float* __restrict__ state_base,
                 float* __restrict__ out_base,
                 const float* __restrict__ ws,
                 int t) {
    __shared__ half_t tlh[TR * TSTR];   // x_h tile, 17472 B
    __shared__ half_t tll[TR * TSTR];   // x_l tile, 17472 B

    const int tid = threadIdx.x;
    const int lane = tid & 63, w = tid >> 6;          // 4 waves
    const int X0 = blockIdx.x * 64, Y0 = blockIdx.y * 64, b = blockIdx.z;

    const float* __restrict__ in  = state_base + (size_t)(b * NSLICE + (t - 1)) * IMG;
    float* __restrict__ outp      = out_base   + (size_t)(b * NSLICE + t) * IMG;

    // stage 84 x 96 fp32 -> (x_h, x_l) fp16 tiles; cols gx in [X0-16, X0+80)
    for (int u = tid; u < TR * 12; u += 256) {
        int r = u / 12, ch = u - r * 12;
        int gr = (Y0 + r - 10) & MASK;
        int gc = X0 + 8 * ch - 16;
        float4 a  = *(const float4*)&in[gr * HW + (gc & MASK)];
        float4 c2 = *(const float4*)&in[gr * HW + ((gc + 4) & MASK)];
        float v[8] = {a.x, a.y, a.z, a.w, c2.x, c2.y, c2.z, c2.w};
        f16x8 hh, hl;
        #pragma unroll
        for (int q = 0; q < 8; ++q) {
            half_t h = (half_t)v[q];
            hh[q] = h;
            hl[q] = (half_t)(v[q] - (float)h);
        }
        *(f16x8*)&tlh[r * TSTR + 8 * ch] = hh;
        *(f16x8*)&tll[r * TSTR + 8 * ch] = hl;
    }

    // prefetch fp32 residual centers (L2-hot) while staging drains
    const int gy0 = Y0 + 16 * w + (((lane >> 4) & 3) << 2);
    const int gxb = X0 + (lane & 15);
    float4 xv0, xv1, xv2, xv3;
    xv0.x = in[(gy0+0)*HW + gxb];      xv0.y = in[(gy0+1)*HW + gxb];
    xv0.z = in[(gy0+2)*HW + gxb];      xv0.w = in[(gy0+3)*HW + gxb];
    xv1.x = in[(gy0+0)*HW + gxb+16];   xv1.y = in[(gy0+1)*HW + gxb+16];
    xv1.z = in[(gy0+2)*HW + gxb+16];   xv1.w = in[(gy0+3)*HW + gxb+16];
    xv2.x = in[(gy0+0)*HW + gxb+32];   xv2.y = in[(gy0+1)*HW + gxb+32];
    xv2.z = in[(gy0+2)*HW + gxb+32];   xv2.w = in[(gy0+3)*HW + gxb+32];
    xv3.x = in[(gy0+0)*HW + gxb+48];   xv3.y = in[(gy0+1)*HW + gxb+48];
    xv3.z = in[(gy0+2)*HW + gxb+48];   xv3.w = in[(gy0+3)*HW + gxb+48];

    __syncthreads();

    const f16x8* bglob = (const f16x8*)((const unsigned short*)ws + WSB_OFF);
    const int rowoff = (16 * w + (lane & 15)) * TSTR + ((lane >> 4) << 3);

    f32x4 acc0 = {0.f,0.f,0.f,0.f}, acc1 = acc0, acc2 = acc0, acc3 = acc0;

    // double-buffered A-frags (named regs) and B-sets
    f16x8 ah0,ah1,ah2,ah3,ah4, al0,al1,al2,al3,al4;   // buffer A
    f16x8 ch0,ch1,ch2,ch3,ch4, cl0,cl1,cl2,cl3,cl4;   // buffer C
    f16x8 b0h0,b0l0,b0h1,b0l1;                         // B set 0
    f16x8 b1h0,b1l0,b1h1,b1l1;                         // B set 1

    auto LOADA = [&](f16x8& h0, f16x8& h1, f16x8& h2, f16x8& h3, f16x8& h4,
                     f16x8& l0, f16x8& l1, f16x8& l2, f16x8& l3, f16x8& l4,
                     int dy) {
        const half_t* rph = &tlh[rowoff + dy * TSTR];
        const half_t* rpl = &tll[rowoff + dy * TSTR];
        h0 = *(const f16x8*)(rph);      h1 = *(const f16x8*)(rph + 16);
        h2 = *(const f16x8*)(rph + 32); h3 = *(const f16x8*)(rph + 48);
        h4 = *(const f16x8*)(rph + 64);
        l0 = *(const f16x8*)(rpl);      l1 = *(const f16x8*)(rpl + 16);
        l2 = *(const f16x8*)(rpl + 32); l3 = *(const f16x8*)(rpl + 48);
        l4 = *(const f16x8*)(rpl + 64);
    };
    auto LOADB = [&](f16x8& h0, f16x8& l0, f16x8& h1, f16x8& l1, int dy) {
        const f16x8* nb = bglob + dy * 256 + lane;
        h0 = nb[0]; l0 = nb[64]; h1 = nb[128]; l1 = nb[192];
    };
    auto MFMA24 = [&](const f16x8& Ah0, const f16x8& Ah1, const f16x8& Ah2,
                      const f16x8& Ah3, const f16x8& Ah4,
                      const f16x8& Al0, const f16x8& Al1, const f16x8& Al2,
                      const f16x8& Al3, const f16x8& Al4,
                      const f16x8& bh0, const f16x8& bl0,
                      const f16x8& bh1, const f16x8& bl1) {
        __builtin_amdgcn_s_setprio(1);
        acc0 = __builtin_amdgcn_mfma_f32_16x16x32_f16(Ah0, bh0, acc0, 0,0,0);
        acc1 = __builtin_amdgcn_mfma_f32_16x16x32_f16(Ah1, bh0, acc1, 0,0,0);
        acc2 = __builtin_amdgcn_mfma_f32_16x16x32_f16(Ah2, bh0, acc2, 0,0,0);
        acc3 = __builtin_amdgcn_mfma_f32_16x16x32_f16(Ah3, bh0, acc3, 0,0,0);
        acc0 = __builtin_amdgcn_mfma_f32_16x16x32_f16(Ah1, bh1, acc0, 0,0,0);
        acc1 = __builtin_amdgcn_mfma_f32_16x16x32_f16(Ah2, bh1, acc1, 0,0,0);
        acc2 = __builtin_amdgcn_mfma_f32_16x16x32_f16(Ah3, bh1, acc2, 0,0,0);
        acc3 = __builtin_amdgcn_mfma_f32_16x16x32_f16(Ah4, bh1, acc3, 0,0,0);
        acc0 = __builtin_amdgcn_mfma_f32_16x16x32_f16(Ah0, bl0, acc0, 0,0,0);
        acc1 = __builtin_amdgcn_mfma_f32_16x16x32_f16(Ah1, bl0, acc1, 0,0,0);
        acc2 = __builtin_amdgcn_mfma_f32_16x16x32_f16(Ah2, bl0, acc2, 0,0,0);
        acc3 = __builtin_amdgcn_mfma_f32_16x16x32_f16(Ah3, bl0, acc3, 0,0,0);
        acc0 = __builtin_amdgcn_mfma_f32_16x16x32_f16(Ah1, bl1, acc0, 0,0,0);
        acc1 = __builtin_amdgcn_mfma_f32_16x16x32_f16(Ah2, bl1, acc1, 0,0,0);
        acc2 = __builtin_amdgcn_mfma_f32_16x16x32_f16(Ah3, bl1, acc2, 0,0,0);
        acc3 = __builtin_amdgcn_mfma_f32_16x16x32_f16(Ah4, bl1, acc3, 0,0,0);
        acc0 = __builtin_amdgcn_mfma_f32_16x16x32_f16(Al0, bh0, acc0, 0,0,0);
        acc1 = __builtin_amdgcn_mfma_f32_16x16x32_f16(Al1, bh0, acc1, 0,0,0);
        acc2 = __builtin_amdgcn_mfma_f32_16x16x32_f16(Al2, bh0, acc2, 0,0,0);
        acc3 = __builtin_amdgcn_mfma_f32_16x16x32_f16(Al3, bh0, acc3, 0,0,0);
        acc0 = __builtin_amdgcn_mfma_f32_16x16x32_f16(Al1, bh1, acc0, 0,0,0);
        acc1 = __builtin_amdgcn_mfma_f32_16x16x32_f16(Al2, bh1, acc1, 0,0,0);
        acc2 = __builtin_amdgcn_mfma_f32_16x16x32_f16(Al3, bh1, acc2, 0,0,0);
        acc3 = __builtin_amdgcn_mfma_f32_16x16x32_f16(Al4, bh1, acc3, 0,0,0);
        __builtin_amdgcn_s_setprio(0);
    };

    // prologue: dy=0 operands + dy=1 B-set
    LOADA(ah0,ah1,ah2,ah3,ah4, al0,al1,al2,al3,al4, 0);
    LOADB(b0h0,b0l0,b0h1,b0l1, 0);
    LOADB(b1h0,b1l0,b1h1,b1l1, 1);

    #pragma unroll 1
    for (int k = 0; k < 10; ++k) {
        const int dy1 = 2*k + 1;
        // --- half 1: issue dy1 A-reads, then MFMA dy=2k ---
        LOADA(ch0,ch1,ch2,ch3,ch4, cl0,cl1,cl2,cl3,cl4, dy1);
        SBAR();                          // pin: reads issued BEFORE MFMA cluster
        MFMA24(ah0,ah1,ah2,ah3,ah4, al0,al1,al2,al3,al4,
               b0h0,b0l0,b0h1,b0l1);
        SBAR();                          // pin: cluster closed
        // --- half 2: issue dy1+1 A-reads + B-loads, then MFMA dy=2k+1 ---
        LOADB(b0h0,b0l0,b0h1,b0l1, dy1 + 1);
        LOADA(ah0,ah1,ah2,ah3,ah4, al0,al1,al2,al3,al4, dy1 + 1);
        SBAR();
        MFMA24(ch0,ch1,ch2,ch3,ch4, cl0,cl1,cl2,cl3,cl4,
               b1h0,b1l0,b1h1,b1l1);
        SBAR();
        if (k < 9) LOADB(b1h0,b1l0,b1h1,b1l1, dy1 + 2);
    }
    MFMA24(ah0,ah1,ah2,ah3,ah4, al0,al1,al2,al3,al4,
           b0h0,b0l0,b0h1,b0l1);                                     // dy = 20

    // D layout: lane l, reg q -> row = (l>>4)*4 + q, col = l&15 (dtype-indep)
    const float C = ws[0];
    auto EPI = [&](const f32x4& a4, const float4& xv, int j) {
        int gx = gxb + 16 * j;
        float cv[4] = {xv.x, xv.y, xv.z, xv.w};
        #pragma unroll
        for (int q = 0; q < 4; ++q) {
            int gy = gy0 + q;
            float a  = cv[q] + C * fmaxf(a4[q], 0.f);
            float e  = __expf(2.f * fabsf(a));        // tanh(|a|) = 1 - 2/(e+1)
            float r  = 1.f - 2.f * __builtin_amdgcn_rcpf(e + 1.f);
            outp[gy * HW + gx] = copysignf(r, a);
        }
    };
    EPI(acc0, xv0, 0); EPI(acc1, xv1, 1); EPI(acc2, xv2, 2); EPI(acc3, xv3, 3);
}

extern "C" void kernel_launch(void* const* d_in, const int* in_sizes, int n_in,
                              void* d_out, int out_size, void* d_ws, size_t ws_size,
                              hipStream_t stream) {
    const float* x  = (const float*)d_in[0];
    const float* w1 = (const float*)d_in[1];
    const float* w2 = (const float*)d_in[2];
    const float* w3 = (const float*)d_in[3];
    float* out = (float*)d_out;
    float* ws  = (float*)d_ws;

    prep_kernel<<<1, 256, 0, stream>>>(w1, w2, w3, ws);
    copy_kernel<<<2048, 256, 0, stream>>>(x, out);

    dim3 grid(8, 8, 8);      // 512 blocks (64x64 out each) = 2/CU
    dim3 block(256);
    for (int t = 1; t <= NSTEP; ++t)
        step_kernel<<<grid, block, 0, stream>>>(out, out, ws, t);
}

// Round 13
// 248.097 us; speedup vs baseline: 1.2048x; 1.2048x over previous
//
#include <hip/hip_runtime.h>
#include <hip/hip_fp16.h>
#include <math.h>

#define HW 512
#define MASK 511
#define IMG (512*512)
#define NSTEP 16
#define NSLICE 17

#define TR 84             // tile rows: [Y0-10, Y0+74)
#define TSTR 104          // ushort stride/row: 208 B = 13 granules (odd -> uniform banks)
#define WSB_OFF 32        // ushort offset of B-frag table in ws

typedef _Float16 half_t;
typedef __attribute__((ext_vector_type(8))) _Float16 f16x8;
typedef __attribute__((ext_vector_type(4))) float f32x4;

#define SBAR() __builtin_amdgcn_sched_barrier(0)

// B-frags (Toeplitz): frag f2 = dy*4 + v*2 + s  (v: dx-window, s: hi/lo split).
// lane l, elem j -> k = 8*(l>>4)+j, n = l&15, d = k-n.
// v=0: B[k][n] = W[dy][d-6]  for d in [6,15]  (dx 0..9,  A-window 16j)
// v=1: B[k][n] = W[dy][d+10] for d in [0,10]  (dx 10..20, A-window 16j+16)
// W = W_h + W_l (fp16 split) => W effectively exact; x is single fp16 (2-pass).
__global__ void prep_kernel(const float* __restrict__ w1,
                            const float* __restrict__ w2,
                            const float* __restrict__ w3,
                            float* __restrict__ ws) {
    int tid = threadIdx.x;
    if (tid == 0) {
        // 1->10->1 MLP on nonneg scalar collapses: C = sum_o w3[o]*max(w2[o],0)
        float c = 0.f;
        for (int o = 0; o < 10; ++o) c += w3[o] * fmaxf(w2[o], 0.f);
        ws[0] = c;
    }
    half_t* wsb = (half_t*)((unsigned short*)ws + WSB_OFF);
    for (int u = tid; u < 84 * 512; u += blockDim.x) {
        int f2 = u >> 9, rem = u & 511, l = rem >> 3, j = rem & 7;
        int dy = f2 >> 2, v = (f2 >> 1) & 1, s = f2 & 1;
        int k = ((l >> 4) << 3) + j, n = l & 15, d = k - n;
        float wf = 0.f;
        if (v == 0) { if (d >= 6 && d <= 15) wf = w1[dy * 21 + d - 6]; }
        else        { if (d >= 0 && d <= 10) wf = w1[dy * 21 + d + 10]; }
        half_t h = (half_t)wf;
        wsb[u] = (s == 0) ? h : (half_t)(wf - (float)h);   // W = W_h + W_l
    }
}

__global__ void copy_kernel(const float* __restrict__ x, float* __restrict__ out) {
    int i = blockIdx.x * blockDim.x + threadIdx.x;   // float4 index
    if (i < 8 * 65536) {
        const float4* in4 = (const float4*)x;
        float4* out4 = (float4*)out;
        int b = i >> 16;
        int off = i & 65535;
        out4[(size_t)b * (NSLICE * 65536) + off] = in4[i];
    }
}

__global__ __launch_bounds__(256, 3)
void step_kernel(const float* __restrict__ state_base,
                 float* __restrict__ out_base,
                 const float* __restrict__ ws,
                 int t) {
    __shared__ half_t tlh[TR * TSTR];   // x fp16 tile, 17472 B (single tile)

    const int tid = threadIdx.x;
    const int lane = tid & 63, w = tid >> 6;          // 4 waves
    const int X0 = blockIdx.x * 64, Y0 = blockIdx.y * 64, b = blockIdx.z;

    const float* __restrict__ in  = state_base + (size_t)(b * NSLICE + (t - 1)) * IMG;
    float* __restrict__ outp      = out_base   + (size_t)(b * NSLICE + t) * IMG;

    // stage 84 x 96 fp32 -> fp16 tile; cols gx in [X0-16, X0+80)
    for (int u = tid; u < TR * 12; u += 256) {
        int r = u / 12, ch = u - r * 12;
        int gr = (Y0 + r - 10) & MASK;
        int gc = X0 + 8 * ch - 16;
        float4 a  = *(const float4*)&in[gr * HW + (gc & MASK)];
        float4 c2 = *(const float4*)&in[gr * HW + ((gc + 4) & MASK)];
        float v[8] = {a.x, a.y, a.z, a.w, c2.x, c2.y, c2.z, c2.w};
        f16x8 hh;
        #pragma unroll
        for (int q = 0; q < 8; ++q) hh[q] = (half_t)v[q];
        *(f16x8*)&tlh[r * TSTR + 8 * ch] = hh;
    }

    // prefetch fp32 residual centers (L2-hot) while staging drains
    const int gy0 = Y0 + 16 * w + (((lane >> 4) & 3) << 2);
    const int gxb = X0 + (lane & 15);
    float4 xv0, xv1, xv2, xv3;
    xv0.x = in[(gy0+0)*HW + gxb];      xv0.y = in[(gy0+1)*HW + gxb];
    xv0.z = in[(gy0+2)*HW + gxb];      xv0.w = in[(gy0+3)*HW + gxb];
    xv1.x = in[(gy0+0)*HW + gxb+16];   xv1.y = in[(gy0+1)*HW + gxb+16];
    xv1.z = in[(gy0+2)*HW + gxb+16];   xv1.w = in[(gy0+3)*HW + gxb+16];
    xv2.x = in[(gy0+0)*HW + gxb+32];   xv2.y = in[(gy0+1)*HW + gxb+32];
    xv2.z = in[(gy0+2)*HW + gxb+32];   xv2.w = in[(gy0+3)*HW + gxb+32];
    xv3.x = in[(gy0+0)*HW + gxb+48];   xv3.y = in[(gy0+1)*HW + gxb+48];
    xv3.z = in[(gy0+2)*HW + gxb+48];   xv3.w = in[(gy0+3)*HW + gxb+48];

    __syncthreads();

    const f16x8* bglob = (const f16x8*)((const unsigned short*)ws + WSB_OFF);
    const int rowoff = (16 * w + (lane & 15)) * TSTR + ((lane >> 4) << 3);

    f32x4 acc0 = {0.f,0.f,0.f,0.f}, acc1 = acc0, acc2 = acc0, acc3 = acc0;

    // double-buffered A-frags (named regs) and B-sets
    f16x8 a0,a1,a2,a3,a4;           // buffer A
    f16x8 c0,c1,c2,c3,c4;           // buffer C
    f16x8 b0h0,b0l0,b0h1,b0l1;      // B set 0
    f16x8 b1h0,b1l0,b1h1,b1l1;      // B set 1

    auto LOADA = [&](f16x8& h0, f16x8& h1, f16x8& h2, f16x8& h3, f16x8& h4,
                     int dy) {
        const half_t* rph = &tlh[rowoff + dy * TSTR];
        h0 = *(const f16x8*)(rph);      h1 = *(const f16x8*)(rph + 16);
        h2 = *(const f16x8*)(rph + 32); h3 = *(const f16x8*)(rph + 48);
        h4 = *(const f16x8*)(rph + 64);
    };
    auto LOADB = [&](f16x8& h0, f16x8& l0, f16x8& h1, f16x8& l1, int dy) {
        const f16x8* nb = bglob + dy * 256 + lane;
        h0 = nb[0]; l0 = nb[64]; h1 = nb[128]; l1 = nb[192];
    };
    auto MFMA16 = [&](const f16x8& A0, const f16x8& A1, const f16x8& A2,
                      const f16x8& A3, const f16x8& A4,
                      const f16x8& bh0, const f16x8& bl0,
                      const f16x8& bh1, const f16x8& bl1) {
        __builtin_amdgcn_s_setprio(1);
        acc0 = __builtin_amdgcn_mfma_f32_16x16x32_f16(A0, bh0, acc0, 0,0,0);
        acc1 = __builtin_amdgcn_mfma_f32_16x16x32_f16(A1, bh0, acc1, 0,0,0);
        acc2 = __builtin_amdgcn_mfma_f32_16x16x32_f16(A2, bh0, acc2, 0,0,0);
        acc3 = __builtin_amdgcn_mfma_f32_16x16x32_f16(A3, bh0, acc3, 0,0,0);
        acc0 = __builtin_amdgcn_mfma_f32_16x16x32_f16(A1, bh1, acc0, 0,0,0);
        acc1 = __builtin_amdgcn_mfma_f32_16x16x32_f16(A2, bh1, acc1, 0,0,0);
        acc2 = __builtin_amdgcn_mfma_f32_16x16x32_f16(A3, bh1, acc2, 0,0,0);
        acc3 = __builtin_amdgcn_mfma_f32_16x16x32_f16(A4, bh1, acc3, 0,0,0);
        acc0 = __builtin_amdgcn_mfma_f32_16x16x32_f16(A0, bl0, acc0, 0,0,0);
        acc1 = __builtin_amdgcn_mfma_f32_16x16x32_f16(A1, bl0, acc1, 0,0,0);
        acc2 = __builtin_amdgcn_mfma_f32_16x16x32_f16(A2, bl0, acc2, 0,0,0);
        acc3 = __builtin_amdgcn_mfma_f32_16x16x32_f16(A3, bl0, acc3, 0,0,0);
        acc0 = __builtin_amdgcn_mfma_f32_16x16x32_f16(A1, bl1, acc0, 0,0,0);
        acc1 = __builtin_amdgcn_mfma_f32_16x16x32_f16(A2, bl1, acc1, 0,0,0);
        acc2 = __builtin_amdgcn_mfma_f32_16x16x32_f16(A3, bl1, acc2, 0,0,0);
        acc3 = __builtin_amdgcn_mfma_f32_16x16x32_f16(A4, bl1, acc3, 0,0,0);
        __builtin_amdgcn_s_setprio(0);
    };

    // prologue: dy=0 operands + dy=1 B-set
    LOADA(a0,a1,a2,a3,a4, 0);
    LOADB(b0h0,b0l0,b0h1,b0l1, 0);
    LOADB(b1h0,b1l0,b1h1,b1l1, 1);

    #pragma unroll 1
    for (int k = 0; k < 10; ++k) {
        const int dy1 = 2*k + 1;
        // --- half 1: issue dy1 A-reads, then MFMA dy=2k ---
        LOADA(c0,c1,c2,c3,c4, dy1);
        SBAR();
        MFMA16(a0,a1,a2,a3,a4, b0h0,b0l0,b0h1,b0l1);
        SBAR();
        // --- half 2: issue dy1+1 A-reads + B-loads, then MFMA dy=2k+1 ---
        LOADB(b0h0,b0l0,b0h1,b0l1, dy1 + 1);
        LOADA(a0,a1,a2,a3,a4, dy1 + 1);
        SBAR();
        MFMA16(c0,c1,c2,c3,c4, b1h0,b1l0,b1h1,b1l1);
        SBAR();
        if (k < 9) LOADB(b1h0,b1l0,b1h1,b1l1, dy1 + 2);
    }
    MFMA16(a0,a1,a2,a3,a4, b0h0,b0l0,b0h1,b0l1);         // dy = 20

    // D layout: lane l, reg q -> row = (l>>4)*4 + q, col = l&15 (dtype-indep)
    const float C = ws[0];
    auto EPI = [&](const f32x4& a4v, const float4& xv, int j) {
        int gx = gxb + 16 * j;
        float cv[4] = {xv.x, xv.y, xv.z, xv.w};
        #pragma unroll
        for (int q = 0; q < 4; ++q) {
            int gy = gy0 + q;
            float a  = cv[q] + C * fmaxf(a4v[q], 0.f);
            float e  = __expf(2.f * fabsf(a));        // tanh(|a|) = 1 - 2/(e+1)
            float r  = 1.f - 2.f * __builtin_amdgcn_rcpf(e + 1.f);
            outp[gy * HW + gx] = copysignf(r, a);
        }
    };
    EPI(acc0, xv0, 0); EPI(acc1, xv1, 1); EPI(acc2, xv2, 2); EPI(acc3, xv3, 3);
}

extern "C" void kernel_launch(void* const* d_in, const int* in_sizes, int n_in,
                              void* d_out, int out_size, void* d_ws, size_t ws_size,
                              hipStream_t stream) {
    const float* x  = (const float*)d_in[0];
    const float* w1 = (const float*)d_in[1];
    const float* w2 = (const float*)d_in[2];
    const float* w3 = (const float*)d_in[3];
    float* out = (float*)d_out;
    float* ws  = (float*)d_ws;

    prep_kernel<<<1, 256, 0, stream>>>(w1, w2, w3, ws);
    copy_kernel<<<2048, 256, 0, stream>>>(x, out);

    dim3 grid(8, 8, 8);      // 512 blocks (64x64 out each); 17.5KB LDS -> 3/CU target
    dim3 block(256);
    for (int t = 1; t <= NSTEP; ++t)
        step_kernel<<<grid, block, 0, stream>>>(out, out, ws, t);
}